// Round 17
// baseline (255.654 us; speedup 1.0000x reference)
//
#include <hip/hip_runtime.h>
#include <hip/hip_fp16.h>
#include <math.h>

#define NT 100000
#define B_GRAPHS 50
#define NE 1600000
#define V 15000
#define D 128
#define NODES_PER_GRAPH (NT / B_GRAPHS)   // 2000

#define POOL_N (B_GRAPHS * D + B_GRAPHS)  // 6450

#define BSH 8
#define BIN_DSTS 256
#define NBIN ((NT + BIN_DSTS - 1) / BIN_DSTS)   // 391
#define SLACK (3 * BIN_DSTS)                    // 768 (worst-case row padding)
#define EPB 4096                                // edges per binfill block
#define NFB ((NE + EPB - 1) / EPB)              // 391
#define BUF_SORT 5632                           // per-bin LDS record cap
#define STAGE_STRIDE 4608                       // max bin cnt ~4300 (8 sigma)
#define PAY_STRIDE (STAGE_STRIDE + SLACK)       // 5376, x4 aligned
#define PAY_TAIL 512
#define PR 16
#define PROJ_BLOCKS ((V + PR - 1) / PR)         // 938

// ---- e5m2 helpers ----
__device__ __forceinline__ unsigned enc2_e5m2(float a, float b) {
  unsigned ha = __half_as_ushort(__float2half(a));
  unsigned hb = __half_as_ushort(__float2half(b));
  ha = ((ha + 0x7fu + ((ha >> 8) & 1u)) >> 8) & 0xffu;
  hb = ((hb + 0x7fu + ((hb >> 8) & 1u)) >> 8) & 0xffu;
  return ha | (hb << 8);
}
__device__ __forceinline__ unsigned enc4_e5m2(float a, float b, float c, float d) {
  return enc2_e5m2(a, b) | (enc2_e5m2(c, d) << 16);
}

// ---- payload pick / consume (packed fp16) ----
template<bool USE_WID>
__device__ __forceinline__ int pick_idx(const int4& q, int half) {
  int lo = USE_WID ? (q.x & 0xffff) : q.y;
  int hi = USE_WID ? (q.z & 0xffff) : q.w;
  return half ? hi : lo;
}
__device__ __forceinline__ void consume2h(const int4& q, unsigned v, int half,
                                          __half2& A01, __half2& A23, __half2& SW) {
  unsigned wm = (unsigned)(half ? q.z : q.x);
  unsigned wd = (wm >> 16) | (wm & 0xffff0000u);
  unsigned hp0 = ((v & 0xffu) << 8) | ((v & 0xff00u) << 16);
  unsigned hp1 = ((v >> 8) & 0xff00u) | (v & 0xff000000u);
  __half2 w2 = *(__half2*)&wd;
  A01 = __hfma2(w2, *(__half2*)&hp0, A01);
  A23 = __hfma2(w2, *(__half2*)&hp1, A23);
  SW = __hadd2(SW, w2);
}
__device__ __forceinline__ void consume2h_ns(const int4& q, unsigned v, int half,
                                             __half2& A01, __half2& A23) {
  unsigned wm = (unsigned)(half ? q.z : q.x);
  unsigned wd = (wm >> 16) | (wm & 0xffff0000u);
  unsigned hp0 = ((v & 0xffu) << 8) | ((v & 0xff00u) << 16);
  unsigned hp1 = ((v >> 8) & 0xff00u) | (v & 0xff000000u);
  __half2 w2 = *(__half2*)&wd;
  A01 = __hfma2(w2, *(__half2*)&hp0, A01);
  A23 = __hfma2(w2, *(__half2*)&hp1, A23);
}
__device__ __forceinline__ int4 ld2s(const int2* bp, int i) {
  int2 a = bp[i], c = bp[i + 1];
  return make_int4(a.x, a.y, c.x, c.y);
}

// ---------- K1: merged binfill (blocks < NFB) + project (blocks >= NFB) ----------
// binfill record: .x = w_bf16<<16 | wid (14b) ; .y = src (17b) | dstLocal<<17 (8b)
__global__ __launch_bounds__(512)
void k_pb(const float* __restrict__ embeds, const float* __restrict__ W1,
          const float* __restrict__ b1, unsigned* __restrict__ P1p8,
          float* __restrict__ pool, int2* __restrict__ payTail,
          const int* __restrict__ src, const int* __restrict__ dst,
          const float* __restrict__ ew, const int* __restrict__ node_ids,
          int* __restrict__ binCursor, int2* __restrict__ stage) {
  __shared__ union {
    struct {
      int h[512], sc[512], gbase[512], cur[512];
      int wsum[8], woff[8];
      unsigned short binOf[EPB];    // 8 KB
      int2 buf[EPB];                // 32 KB
    } f;
    struct {
      float sE[PR][D];              // 8 KB
      float sO[PR][D];              // 8 KB
    } p;
  } U;
  int t = threadIdx.x;
  if (blockIdx.x < NFB) {
    // ================= binfill path =================
    int lane = t & 63, wv = t >> 6;
    U.f.h[t] = 0;
    __syncthreads();
    int base = blockIdx.x * EPB;
    int d_[EPB / 512], b_[EPB / 512];
#pragma unroll
    for (int i = 0; i < EPB / 512; ++i) {
      int e = base + i * 512 + t;
      int d = (e < NE) ? dst[e] : -1;
      d_[i] = d;
      b_[i] = (d >= 0) ? (d >> BSH) : -1;
      if (d >= 0) atomicAdd(&U.f.h[b_[i]], 1);
    }
    __syncthreads();
    int c = U.f.h[t];
    int v = c;                                // wave-inclusive scan
#pragma unroll
    for (int off = 1; off < 64; off <<= 1) {
      int x = __shfl_up(v, off);
      if (lane >= off) v += x;
    }
    if (lane == 63) U.f.wsum[wv] = v;
    __syncthreads();
    if (t == 0) {
      int a = 0;
#pragma unroll
      for (int i = 0; i < 8; ++i) { U.f.woff[i] = a; a += U.f.wsum[i]; }
    }
    __syncthreads();
    int incl = v + U.f.woff[wv];
    U.f.sc[t] = incl;
    U.f.cur[t] = incl - c;
    if (t < NBIN && c > 0) U.f.gbase[t] = atomicAdd(&binCursor[t], c);
    __syncthreads();
    int total = U.f.sc[511];
#pragma unroll
    for (int i = 0; i < EPB / 512; ++i) {
      int e = base + i * 512 + t;
      if (e < NE) {
        int s = src[e];
        unsigned uw = __float_as_uint(ew[e]);
        unsigned wb = (uw + 0x7fffu + ((uw >> 16) & 1u)) & 0xffff0000u;  // RN bf16
        int wid = node_ids[s];
        int dl = d_[i] & (BIN_DSTS - 1);
        int p = atomicAdd(&U.f.cur[b_[i]], 1);
        U.f.buf[p] = make_int2((int)(wb | (unsigned)wid), s | (dl << 17));
        U.f.binOf[p] = (unsigned short)b_[i];
      }
    }
    __syncthreads();
    for (int i = t; i < total; i += 512) {    // record-parallel coalesced flush
      int b = U.f.binOf[i];
      int local = i - (U.f.sc[b] - U.f.h[b]);
      stage[(size_t)b * STAGE_STRIDE + U.f.gbase[b] + local] = U.f.buf[i];
    }
  } else {
    // ================= project path =================
    int pb = blockIdx.x - NFB;
    if (pb == 0) {                 // zero pool + payTail (consumed by agg2, later)
      for (int i = t; i < POOL_N; i += 512) pool[i] = 0.f;
      for (int i = t; i < PAY_TAIL; i += 512) payTail[i] = make_int2(0, 0);
    }
    int row0 = pb * PR;
    for (int i = t; i < PR * D; i += 512) {
      int r = i >> 7, c = i & 127;
      int vv = row0 + r;
      U.p.sE[r][c] = (vv < V) ? embeds[(size_t)vv * D + c] : 0.f;
    }
    __syncthreads();
    int c = t & 127, rg = (t >> 7) * 4;      // 4 rows per thread
    float bd = b1[c];
    float acc[4];
#pragma unroll
    for (int r = 0; r < 4; ++r) acc[r] = bd;
#pragma unroll 4
    for (int k = 0; k < D; ++k) {
      float w = W1[k * D + c];
#pragma unroll
      for (int r = 0; r < 4; ++r) acc[r] = fmaf(U.p.sE[rg + r][k], w, acc[r]);
    }
#pragma unroll
    for (int r = 0; r < 4; ++r) U.p.sO[rg + r][c] = acc[r];
    __syncthreads();
    {
      int r = t >> 5, li = t & 31;           // 512 = 16 rows x 32
      int vv = row0 + r;
      if (vv < V)
        P1p8[(size_t)vv * 32 + li] =
            enc4_e5m2(U.p.sO[r][4 * li], U.p.sO[r][4 * li + 1],
                      U.p.sO[r][4 * li + 2], U.p.sO[r][4 * li + 3]);
    }
  }
}

// ---------- K2: per-bin counting-sort + FUSED layer-1 aggregate ----------
// Builds the padded per-dst CSR in LDS, flushes it to pay, then computes
// layer-1 (mean via folded w' + leaky -> h1p8) for this bin's 256 dsts with
// payload read straight from LDS.
__global__ __launch_bounds__(512)
void k_sortagg(const int2* __restrict__ stage, const int* __restrict__ binCnt,
               const unsigned* __restrict__ P1p8,
               int* __restrict__ rowD, int* __restrict__ cntD,
               int2* __restrict__ pay, unsigned* __restrict__ h1p8) {
  __shared__ int h2[BIN_DSTS], cur2[BIN_DSTS], offArr[BIN_DSTS];
  __shared__ float invD[BIN_DSTS];
  __shared__ int wsum4[4], woff4[4];
  __shared__ int sh_end;
  __shared__ int2 buf[BUF_SORT];            // 44 KB
  int b = blockIdx.x, t = threadIdx.x;
  int lane = t & 63, wv = t >> 6;
  int cnt = binCnt[b];
  int sb = b * STAGE_STRIDE;
  int pbase = b * PAY_STRIDE;
  int dst0 = b << BSH;
  if (t < BIN_DSTS) h2[t] = 0;
  __syncthreads();
  for (int i = t; i < cnt; i += 512)
    atomicAdd(&h2[(stage[sb + i].y >> 17) & 255], 1);
  __syncthreads();
  int c = (t < BIN_DSTS) ? h2[t] : 0;
  int pc = (c + 3) & ~3;                    // row padded to x4
  int v = (t < BIN_DSTS) ? pc : 0;
#pragma unroll
  for (int off = 1; off < 64; off <<= 1) {  // wave-inclusive scan
    int x = __shfl_up(v, off);
    if (lane >= off) v += x;
  }
  if (lane == 63 && wv < 4) wsum4[wv] = v;
  __syncthreads();
  if (t == 0) {
    int a = 0;
#pragma unroll
    for (int i = 0; i < 4; ++i) { woff4[i] = a; a += wsum4[i]; }
    sh_end = a;
  }
  __syncthreads();
  if (t < BIN_DSTS) {
    int myoff = v + woff4[wv] - pc;
    invD[t] = (c > 0) ? (1.0f / (float)c) : 0.0f;
    cur2[t] = myoff;
    offArr[t] = myoff;
    int n = dst0 + t;
    if (n < NT) { rowD[n] = pbase + myoff; cntD[n] = c; }
  }
  __syncthreads();
  int end = sh_end + 24;                    // guard for gather prologue overrun
  if (end > PAY_STRIDE) end = PAY_STRIDE;
  for (int i = t; i < end; i += 512) buf[i] = make_int2(0, 0);
  __syncthreads();
  for (int i = t; i < cnt; i += 512) {
    int2 r = stage[sb + i];
    int dl = (r.y >> 17) & 255;
    float w = __uint_as_float((unsigned)r.x & 0xffff0000u);
    float wp = w * invD[dl];
    unsigned wh = (unsigned)__half_as_ushort(__float2half(wp));   // fp16 w'
    int p = atomicAdd(&cur2[dl], 1);
    buf[p] = make_int2((int)((wh << 16) | ((unsigned)r.x & 0xffffu)), r.y & 0x1ffff);
  }
  __syncthreads();
  // flush CSR to global (incl. zero guard) — agg2 consumes it
  for (int i = t; i < end; i += 512) pay[pbase + i] = buf[i];
  // ---- fused layer-1: payload from LDS, P1p8 gather from L2 ----
  int li = lane & 31, half = lane >> 5;
  for (int j = 0; j < 32; ++j) {
    int dl = wv * 32 + j;
    int beg = offArr[dl];
    int cn = h2[dl];
    int G = (cn + 3) >> 2;
    __half2 A01 = __half2half2(__float2half(0.f));
    __half2 A23 = A01;
    int4 qa0 = ld2s(buf, beg + 0), qb0 = ld2s(buf, beg + 2);
    int4 qa1 = ld2s(buf, beg + 4), qb1 = ld2s(buf, beg + 6);
    unsigned va0 = P1p8[(size_t)pick_idx<true>(qa0, half) * 32 + li];
    unsigned vb0 = P1p8[(size_t)pick_idx<true>(qb0, half) * 32 + li];
    unsigned va1 = P1p8[(size_t)pick_idx<true>(qa1, half) * 32 + li];
    unsigned vb1 = P1p8[(size_t)pick_idx<true>(qb1, half) * 32 + li];
    for (int g = 0; g < G; ++g) {
      int4 qa2 = ld2s(buf, beg + 4 * g + 8);
      int4 qb2 = ld2s(buf, beg + 4 * g + 10);
      unsigned vn0 = P1p8[(size_t)pick_idx<true>(qa2, half) * 32 + li];
      unsigned vn1 = P1p8[(size_t)pick_idx<true>(qb2, half) * 32 + li];
      consume2h_ns(qa0, va0, half, A01, A23);
      consume2h_ns(qb0, vb0, half, A01, A23);
      qa0 = qa1; qb0 = qb1; qa1 = qa2; qb1 = qb2;
      va0 = va1; vb0 = vb1; va1 = vn0; vb1 = vn1;
    }
    float2 f01 = __half22float2(A01);
    float2 f23 = __half22float2(A23);
    float a0 = f01.x, a1 = f01.y, a2 = f23.x, a3 = f23.y;
    a0 += __shfl_down(a0, 32);
    a1 += __shfl_down(a1, 32);
    a2 += __shfl_down(a2, 32);
    a3 += __shfl_down(a3, 32);
    if (lane < 32) {
      int n = dst0 + dl;
      if (n < NT) {
        float x0 = a0, x1 = a1, x2 = a2, x3 = a3;   // w'=w/deg -> mean
        x0 = (x0 > 0.f) ? x0 : 0.01f * x0;
        x1 = (x1 > 0.f) ? x1 : 0.01f * x1;
        x2 = (x2 > 0.f) ? x2 : 0.01f * x2;
        x3 = (x3 > 0.f) ? x3 : 0.01f * x3;
        h1p8[(size_t)n * 32 + li] = enc4_e5m2(x0, x1, x2, x3);
      }
    }
  }
}

// ---- global-payload row gather (agg2): 4 edges/iter, branch-free, depth-3 ----
__device__ __forceinline__ void gather_row_g(const int2* __restrict__ pay,
                                             const unsigned* __restrict__ tab,
                                             int beg, int cnt, int li, int half,
                                             __half2& A01, __half2& A23, __half2& SW) {
  int G = (cnt + 3) >> 2;
  const int4* __restrict__ pp = (const int4*)(pay + beg);
  int4 q0a = pp[0], q0b = pp[1];
  int4 q1a = pp[2], q1b = pp[3];
  int4 q2a = pp[4], q2b = pp[5];
  int4 q3a = pp[6], q3b = pp[7];
  int4 q4a = pp[8], q4b = pp[9];
  unsigned va0 = tab[(size_t)pick_idx<false>(q0a, half) * 32 + li];
  unsigned vb0 = tab[(size_t)pick_idx<false>(q0b, half) * 32 + li];
  unsigned va1 = tab[(size_t)pick_idx<false>(q1a, half) * 32 + li];
  unsigned vb1 = tab[(size_t)pick_idx<false>(q1b, half) * 32 + li];
  unsigned va2 = tab[(size_t)pick_idx<false>(q2a, half) * 32 + li];
  unsigned vb2 = tab[(size_t)pick_idx<false>(q2b, half) * 32 + li];
  for (int g = 0; g < G; ++g) {
    unsigned vn0 = tab[(size_t)pick_idx<false>(q3a, half) * 32 + li];
    unsigned vn1 = tab[(size_t)pick_idx<false>(q3b, half) * 32 + li];
    int4 qna = pp[2 * g + 10];
    int4 qnb = pp[2 * g + 11];
    consume2h(q0a, va0, half, A01, A23, SW);
    consume2h(q0b, vb0, half, A01, A23, SW);
    q0a = q1a; q0b = q1b; q1a = q2a; q1b = q2b; q2a = q3a; q2b = q3b;
    q3a = q4a; q3b = q4b; q4a = qna; q4b = qnb;
    va0 = va1; vb0 = vb1; va1 = va2; vb1 = vb2; va2 = vn0; vb2 = vn1;
  }
}

// ---------- K3: layer-2 per-node gather fused with per-graph pooling ----------
#define NPW2 10
#define BLKS_PER_G (NODES_PER_GRAPH / (4 * NPW2))   // 50
__global__ void k_agg2(const int2* __restrict__ pay,
                       const int* __restrict__ rowD, const int* __restrict__ cntD,
                       const unsigned* __restrict__ h1p8,
                       float* __restrict__ pool) {
  int g = blockIdx.x / BLKS_PER_G;
  int chunk = blockIdx.x % BLKS_PER_G;
  int w = threadIdx.x >> 6, lane = threadIdx.x & 63;
  int li = lane & 31, half = lane >> 5;
  int nbase = g * NODES_PER_GRAPH + chunk * (4 * NPW2) + w * NPW2;
  __half2 A01 = __half2half2(__float2half(0.f));
  __half2 A23 = A01, SW = A01;
  for (int i = 0; i < NPW2; ++i) {
    int n = nbase + i;
    int beg = __builtin_amdgcn_readfirstlane(rowD[n]);
    int cnt = __builtin_amdgcn_readfirstlane(cntD[n]);
    gather_row_g(pay, h1p8, beg, cnt, li, half, A01, A23, SW);
  }
  float2 f01 = __half22float2(A01);
  float2 f23 = __half22float2(A23);
  float s0 = f01.x, s1 = f01.y, s2 = f23.x, s3 = f23.y;
  float sc = __low2float(SW);
  s0 += __shfl_down(s0, 32);
  s1 += __shfl_down(s1, 32);
  s2 += __shfl_down(s2, 32);
  s3 += __shfl_down(s3, 32);
  sc += __shfl_down(sc, 32);
  __shared__ float sS[4 * 128];
  __shared__ float sC[4];
  if (lane < 32) {
    sS[w * 128 + 4 * li + 0] = s0;
    sS[w * 128 + 4 * li + 1] = s1;
    sS[w * 128 + 4 * li + 2] = s2;
    sS[w * 128 + 4 * li + 3] = s3;
  }
  if (lane == 0) sC[w] = sc;
  __syncthreads();
  int t = threadIdx.x;
  if (t < 128) {
    float v = sS[t] + sS[128 + t] + sS[256 + t] + sS[384 + t];
    atomicAdd(&pool[g * D + t], v);
  }
  if (t == 0) atomicAdd(&pool[B_GRAPHS * D + g], sC[0] + sC[1] + sC[2] + sC[3]);
}

// ---------- K4: head — wave-parallel, barrier-light ----------
__global__ void k_final(const float* __restrict__ poolS, const float* __restrict__ poolC,
                        const float* __restrict__ W2, const float* __restrict__ b2,
                        const float* __restrict__ W_out, const float* __restrict__ b_out,
                        const float* __restrict__ y, float* __restrict__ out) {
  __shared__ float w2o[D];
  __shared__ float s2oArr[D];
  __shared__ float s2o_sh;
  __shared__ float logits[64];
  int t = threadIdx.x;                     // 256 threads = 4 waves
  int w = t >> 6, lane = t & 63;
  if (t < D) {
    float acc = 0.f;
    for (int d = 0; d < D; ++d) acc = fmaf(W2[t * D + d], W_out[d], acc);
    w2o[t] = acc;
  } else {
    int j = t - D;
    s2oArr[j] = b2[j] * W_out[j];
  }
  __syncthreads();
  if (t < 64) {
    float v = s2oArr[lane] + s2oArr[64 + lane];
#pragma unroll
    for (int off = 32; off > 0; off >>= 1) v += __shfl_down(v, off);
    if (lane == 0) s2o_sh = v;
  }
  __syncthreads();
  float s2o = s2o_sh;
  float bout = b_out[0];
  const float invN = 1.0f / (float)NODES_PER_GRAPH;
  for (int g = w; g < B_GRAPHS; g += 4) {
    float v = poolS[g * D + lane] * w2o[lane]
            + poolS[g * D + 64 + lane] * w2o[64 + lane];
#pragma unroll
    for (int off = 32; off > 0; off >>= 1) v += __shfl_down(v, off);
    if (lane == 0) {
      float l = v * invN + poolC[g] * invN * s2o + bout;
      logits[g] = l;
      out[1 + g] = 1.0f / (1.0f + expf(-l));         // y_pred
    }
  }
  __syncthreads();
  if (t < 64) {
    float term = 0.f;
    if (lane < B_GRAPHS) {
      float l = logits[lane];
      term = fmaxf(l, 0.f) - l * y[lane] + log1pf(expf(-fabsf(l)));
    }
#pragma unroll
    for (int off = 32; off > 0; off >>= 1) term += __shfl_down(term, off);
    if (lane == 0) out[0] = term / (float)B_GRAPHS;  // loss
  }
}

extern "C" void kernel_launch(void* const* d_in, const int* in_sizes, int n_in,
                              void* d_out, int out_size, void* d_ws, size_t ws_size,
                              hipStream_t stream) {
  const int*   node_ids = (const int*)d_in[0];
  const int*   src      = (const int*)d_in[1];
  const int*   dst      = (const int*)d_in[2];
  const float* ew       = (const float*)d_in[3];
  const float* y        = (const float*)d_in[4];
  const float* embeds   = (const float*)d_in[5];
  const float* W1       = (const float*)d_in[6];
  const float* b1       = (const float*)d_in[7];
  const float* W2       = (const float*)d_in[8];
  const float* b2       = (const float*)d_in[9];
  const float* W_out    = (const float*)d_in[10];
  const float* b_out    = (const float*)d_in[11];
  float* out = (float*)d_out;
  (void)in_sizes; (void)n_in; (void)out_size; (void)ws_size;

  char* ws = (char*)d_ws;
  size_t off = 0;
  auto alloc = [&](size_t bytes) {
    size_t r = off;
    off = (off + bytes + 511) & ~(size_t)511;
    return r;
  };
  size_t o_binCur = alloc(512 * 4);
  size_t o_pool   = alloc((size_t)POOL_N * 4);
  size_t o_rowD   = alloc((size_t)(NT + 1) * 4);
  size_t o_cntD   = alloc((size_t)NT * 4);
  size_t o_P1p8   = alloc((size_t)V * 32 * 4);                    // 1.92 MB
  size_t o_h1p8   = alloc((size_t)NT * 32 * 4);                   // 12.8 MB
  size_t o_stage  = alloc((size_t)NBIN * STAGE_STRIDE * 8);       // 14.4 MB
  size_t o_pay    = alloc(((size_t)NBIN * PAY_STRIDE + PAY_TAIL) * 8);  // 16.8 MB

  int*      binCursor= (int*)(ws + o_binCur);
  float*    pool     = (float*)(ws + o_pool);
  int*      rowD     = (int*)(ws + o_rowD);
  int*      cntD     = (int*)(ws + o_cntD);
  unsigned* P1p8     = (unsigned*)(ws + o_P1p8);
  unsigned* h1p8     = (unsigned*)(ws + o_h1p8);
  int2*     stage    = (int2*)(ws + o_stage);
  int2*     pay      = (int2*)(ws + o_pay);
  int2*     payTail  = pay + (size_t)NBIN * PAY_STRIDE;

  // 4 kernels + 1 tiny memset (binCursor must be zero before k_pb's binfill blocks)
  hipMemsetAsync(binCursor, 0, 512 * 4, stream);
  k_pb<<<NFB + PROJ_BLOCKS, 512, 0, stream>>>(embeds, W1, b1, P1p8, pool, payTail,
                                              src, dst, ew, node_ids, binCursor, stage);
  k_sortagg<<<NBIN, 512, 0, stream>>>(stage, binCursor, P1p8, rowD, cntD, pay, h1p8);
  k_agg2<<<B_GRAPHS * BLKS_PER_G, 256, 0, stream>>>(pay, rowD, cntD, h1p8, pool);
  k_final<<<1, 256, 0, stream>>>(pool, pool + B_GRAPHS * D, W2, b2, W_out, b_out, y, out);
}

// Round 18
// 253.385 us; speedup vs baseline: 1.0090x; 1.0090x over previous
//
#include <hip/hip_runtime.h>
#include <hip/hip_fp16.h>
#include <math.h>

#define NT 100000
#define B_GRAPHS 50
#define NE 1600000
#define V 15000
#define D 128
#define NODES_PER_GRAPH (NT / B_GRAPHS)   // 2000

#define POOL_N (B_GRAPHS * D + B_GRAPHS)  // 6450

#define BSH 8
#define BIN_DSTS 256
#define NBIN ((NT + BIN_DSTS - 1) / BIN_DSTS)   // 391
#define SLACK (3 * BIN_DSTS)                    // 768 (worst-case row padding)
#define EPB 4096                                // edges per binfill block
#define NFB ((NE + EPB - 1) / EPB)              // 391
#define BUF_SORT 5632                           // per-bin LDS record cap
#define STAGE_STRIDE 4608                       // max bin cnt ~4300 (8 sigma)
#define PAY_STRIDE (STAGE_STRIDE + SLACK)       // 5376, x4 aligned
#define PAY_TAIL 512
#define PR 16
#define PROJ_BLOCKS ((V + PR - 1) / PR)         // 938

// ---- e5m2 helpers ----
__device__ __forceinline__ unsigned enc2_e5m2(float a, float b) {
  unsigned ha = __half_as_ushort(__float2half(a));
  unsigned hb = __half_as_ushort(__float2half(b));
  ha = ((ha + 0x7fu + ((ha >> 8) & 1u)) >> 8) & 0xffu;
  hb = ((hb + 0x7fu + ((hb >> 8) & 1u)) >> 8) & 0xffu;
  return ha | (hb << 8);
}
__device__ __forceinline__ unsigned enc4_e5m2(float a, float b, float c, float d) {
  return enc2_e5m2(a, b) | (enc2_e5m2(c, d) << 16);
}

// ---------- K1: merged binfill (blocks < NFB) + project (blocks >= NFB) ----------
// binfill record: .x = w_bf16<<16 | wid (14b) ; .y = src (17b) | dstLocal<<17 (8b)
__global__ __launch_bounds__(512)
void k_pb(const float* __restrict__ embeds, const float* __restrict__ W1,
          const float* __restrict__ b1, unsigned* __restrict__ P1p8,
          float* __restrict__ pool, int2* __restrict__ payTail,
          const int* __restrict__ src, const int* __restrict__ dst,
          const float* __restrict__ ew, const int* __restrict__ node_ids,
          int* __restrict__ binCursor, int2* __restrict__ stage) {
  __shared__ union {
    struct {
      int h[512], sc[512], gbase[512], cur[512];
      int wsum[8], woff[8];
      unsigned short binOf[EPB];    // 8 KB
      int2 buf[EPB];                // 32 KB
    } f;
    struct {
      float sE[PR][D];              // 8 KB
      float sO[PR][D];              // 8 KB
    } p;
  } U;
  int t = threadIdx.x;
  if (blockIdx.x < NFB) {
    // ================= binfill path =================
    int lane = t & 63, wv = t >> 6;
    U.f.h[t] = 0;
    __syncthreads();
    int base = blockIdx.x * EPB;
    int d_[EPB / 512], b_[EPB / 512];
#pragma unroll
    for (int i = 0; i < EPB / 512; ++i) {
      int e = base + i * 512 + t;
      int d = (e < NE) ? dst[e] : -1;
      d_[i] = d;
      b_[i] = (d >= 0) ? (d >> BSH) : -1;
      if (d >= 0) atomicAdd(&U.f.h[b_[i]], 1);
    }
    __syncthreads();
    int c = U.f.h[t];
    int v = c;                                // wave-inclusive scan
#pragma unroll
    for (int off = 1; off < 64; off <<= 1) {
      int x = __shfl_up(v, off);
      if (lane >= off) v += x;
    }
    if (lane == 63) U.f.wsum[wv] = v;
    __syncthreads();
    if (t == 0) {
      int a = 0;
#pragma unroll
      for (int i = 0; i < 8; ++i) { U.f.woff[i] = a; a += U.f.wsum[i]; }
    }
    __syncthreads();
    int incl = v + U.f.woff[wv];
    U.f.sc[t] = incl;
    U.f.cur[t] = incl - c;
    if (t < NBIN && c > 0) U.f.gbase[t] = atomicAdd(&binCursor[t], c);
    __syncthreads();
    int total = U.f.sc[511];
#pragma unroll
    for (int i = 0; i < EPB / 512; ++i) {
      int e = base + i * 512 + t;
      if (e < NE) {
        int s = src[e];
        unsigned uw = __float_as_uint(ew[e]);
        unsigned wb = (uw + 0x7fffu + ((uw >> 16) & 1u)) & 0xffff0000u;  // RN bf16
        int wid = node_ids[s];
        int dl = d_[i] & (BIN_DSTS - 1);
        int p = atomicAdd(&U.f.cur[b_[i]], 1);
        U.f.buf[p] = make_int2((int)(wb | (unsigned)wid), s | (dl << 17));
        U.f.binOf[p] = (unsigned short)b_[i];
      }
    }
    __syncthreads();
    for (int i = t; i < total; i += 512) {    // record-parallel coalesced flush
      int b = U.f.binOf[i];
      int local = i - (U.f.sc[b] - U.f.h[b]);
      stage[(size_t)b * STAGE_STRIDE + U.f.gbase[b] + local] = U.f.buf[i];
    }
  } else {
    // ================= project path =================
    int pb = blockIdx.x - NFB;
    if (pb == 0) {                 // zero pool + payTail (consumed later)
      for (int i = t; i < POOL_N; i += 512) pool[i] = 0.f;
      for (int i = t; i < PAY_TAIL; i += 512) payTail[i] = make_int2(0, 0);
    }
    int row0 = pb * PR;
    for (int i = t; i < PR * D; i += 512) {
      int r = i >> 7, c = i & 127;
      int vv = row0 + r;
      U.p.sE[r][c] = (vv < V) ? embeds[(size_t)vv * D + c] : 0.f;
    }
    __syncthreads();
    int c = t & 127, rg = (t >> 7) * 4;      // 4 rows per thread
    float bd = b1[c];
    float acc[4];
#pragma unroll
    for (int r = 0; r < 4; ++r) acc[r] = bd;
#pragma unroll 4
    for (int k = 0; k < D; ++k) {
      float w = W1[k * D + c];
#pragma unroll
      for (int r = 0; r < 4; ++r) acc[r] = fmaf(U.p.sE[rg + r][k], w, acc[r]);
    }
#pragma unroll
    for (int r = 0; r < 4; ++r) U.p.sO[rg + r][c] = acc[r];
    __syncthreads();
    {
      int r = t >> 5, li = t & 31;           // 512 = 16 rows x 32
      int vv = row0 + r;
      if (vv < V)
        P1p8[(size_t)vv * 32 + li] =
            enc4_e5m2(U.p.sO[r][4 * li], U.p.sO[r][4 * li + 1],
                      U.p.sO[r][4 * li + 2], U.p.sO[r][4 * li + 3]);
    }
  }
}

// ---------- K2: per-bin LDS counting-sort -> padded per-dst CSR ----------
// 512 threads, wave-level scan, exact-length zero/flush (+24 guard slots).
__global__ __launch_bounds__(512)
void k_binsort(const int2* __restrict__ stage, const int* __restrict__ binCnt,
               int* __restrict__ rowD, int* __restrict__ cntD,
               int2* __restrict__ pay) {
  __shared__ int h2[BIN_DSTS], cur2[BIN_DSTS];
  __shared__ float invD[BIN_DSTS];
  __shared__ int wsum4[4], woff4[4];
  __shared__ int sh_end;
  __shared__ int2 buf[BUF_SORT];            // 44 KB
  int b = blockIdx.x, t = threadIdx.x;
  int lane = t & 63, wv = t >> 6;
  int cnt = binCnt[b];
  int sb = b * STAGE_STRIDE;
  int pb = b * PAY_STRIDE;
  int dst0 = b << BSH;
  if (t < BIN_DSTS) h2[t] = 0;
  __syncthreads();
  for (int i = t; i < cnt; i += 512)
    atomicAdd(&h2[(stage[sb + i].y >> 17) & 255], 1);
  __syncthreads();
  int c = (t < BIN_DSTS) ? h2[t] : 0;
  int pc = (c + 3) & ~3;                    // row padded to x4
  int v = (t < BIN_DSTS) ? pc : 0;
#pragma unroll
  for (int off = 1; off < 64; off <<= 1) {  // wave-inclusive scan
    int x = __shfl_up(v, off);
    if (lane >= off) v += x;
  }
  if (lane == 63 && wv < 4) wsum4[wv] = v;
  __syncthreads();
  if (t == 0) {
    int a = 0;
#pragma unroll
    for (int i = 0; i < 4; ++i) { woff4[i] = a; a += wsum4[i]; }
    sh_end = a;                             // cpL = sum of padded row lengths
  }
  __syncthreads();
  if (t < BIN_DSTS) {
    int myoff = v + woff4[wv] - pc;         // exclusive padded offset
    invD[t] = (c > 0) ? (1.0f / (float)c) : 0.0f;
    cur2[t] = myoff;
    int n = dst0 + t;
    if (n < NT) { rowD[n] = pb + myoff; cntD[n] = c; }
  }
  __syncthreads();
  int end = sh_end + 24;                    // guard slots for prologue overrun
  if (end > PAY_STRIDE) end = PAY_STRIDE;
  for (int i = t; i < end; i += 512) buf[i] = make_int2(0, 0);
  __syncthreads();
  for (int i = t; i < cnt; i += 512) {
    int2 r = stage[sb + i];
    int dl = (r.y >> 17) & 255;
    float w = __uint_as_float((unsigned)r.x & 0xffff0000u);
    float wp = w * invD[dl];
    unsigned wh = (unsigned)__half_as_ushort(__float2half(wp));   // fp16 w'
    int p = atomicAdd(&cur2[dl], 1);
    buf[p] = make_int2((int)((wh << 16) | ((unsigned)r.x & 0xffffu)), r.y & 0x1ffff);
  }
  __syncthreads();
  for (int i = t; i < end; i += 512) pay[pb + i] = buf[i];  // dense, zero slack
}

// ---- shared row-gather: 4 edges/iter, branch-free, packed-fp16 accumulate ----
template<bool USE_WID>
__device__ __forceinline__ int pick_idx(const int4& q, int half) {
  int lo = USE_WID ? (q.x & 0xffff) : q.y;
  int hi = USE_WID ? (q.z & 0xffff) : q.w;
  return half ? hi : lo;
}
__device__ __forceinline__ void consume2h(const int4& q, unsigned v, int half,
                                          __half2& A01, __half2& A23, __half2& SW) {
  unsigned wm = (unsigned)(half ? q.z : q.x);
  unsigned wd = (wm >> 16) | (wm & 0xffff0000u);                 // w' in both halves
  unsigned hp0 = ((v & 0xffu) << 8) | ((v & 0xff00u) << 16);     // dims d, d+1
  unsigned hp1 = ((v >> 8) & 0xff00u) | (v & 0xff000000u);       // dims d+2, d+3
  __half2 w2 = *(__half2*)&wd;
  A01 = __hfma2(w2, *(__half2*)&hp0, A01);
  A23 = __hfma2(w2, *(__half2*)&hp1, A23);
  SW = __hadd2(SW, w2);
}

template<bool USE_WID>
__device__ __forceinline__ void gather_row(const int2* __restrict__ pay,
                                           const unsigned* __restrict__ tab,
                                           int beg, int cnt, int li, int half,
                                           __half2& A01, __half2& A23, __half2& SW) {
  int G = (cnt + 3) >> 2;                       // groups of 4 edges (rows padded)
  const int4* __restrict__ pp = (const int4*)(pay + beg);
  int4 q0a = pp[0], q0b = pp[1];
  int4 q1a = pp[2], q1b = pp[3];
  int4 q2a = pp[4], q2b = pp[5];
  int4 q3a = pp[6], q3b = pp[7];
  int4 q4a = pp[8], q4b = pp[9];
  unsigned va0 = tab[(size_t)pick_idx<USE_WID>(q0a, half) * 32 + li];
  unsigned vb0 = tab[(size_t)pick_idx<USE_WID>(q0b, half) * 32 + li];
  unsigned va1 = tab[(size_t)pick_idx<USE_WID>(q1a, half) * 32 + li];
  unsigned vb1 = tab[(size_t)pick_idx<USE_WID>(q1b, half) * 32 + li];
  unsigned va2 = tab[(size_t)pick_idx<USE_WID>(q2a, half) * 32 + li];
  unsigned vb2 = tab[(size_t)pick_idx<USE_WID>(q2b, half) * 32 + li];
  for (int g = 0; g < G; ++g) {
    unsigned vn0 = tab[(size_t)pick_idx<USE_WID>(q3a, half) * 32 + li];
    unsigned vn1 = tab[(size_t)pick_idx<USE_WID>(q3b, half) * 32 + li];
    int4 qna = pp[2 * g + 10];
    int4 qnb = pp[2 * g + 11];
    consume2h(q0a, va0, half, A01, A23, SW);
    consume2h(q0b, vb0, half, A01, A23, SW);
    q0a = q1a; q0b = q1b; q1a = q2a; q1b = q2b; q2a = q3a; q2b = q3b;
    q3a = q4a; q3b = q4b; q4a = qna; q4b = qnb;
    va0 = va1; vb0 = vb1; va1 = va2; vb1 = vb2; va2 = vn0; vb2 = vn1;
  }
}

// ---------- K3: layer-1 aggregate (w' folded mean) + leaky -> h1p8 ----------
#define NPW1 10
__global__ void k_agg1(const int2* __restrict__ pay,
                       const int* __restrict__ rowD, const int* __restrict__ cntD,
                       const unsigned* __restrict__ P1p8,
                       unsigned* __restrict__ h1p8) {
  int w = threadIdx.x >> 6, lane = threadIdx.x & 63;
  int li = lane & 31, half = lane >> 5;
  int nbase = blockIdx.x * (4 * NPW1) + w * NPW1;
  for (int i = 0; i < NPW1; ++i) {
    int n = nbase + i;
    int beg = __builtin_amdgcn_readfirstlane(rowD[n]);
    int cnt = __builtin_amdgcn_readfirstlane(cntD[n]);
    __half2 A01 = __half2half2(__float2half(0.f));
    __half2 A23 = A01, SW = A01;
    gather_row<true>(pay, P1p8, beg, cnt, li, half, A01, A23, SW);
    float2 f01 = __half22float2(A01);
    float2 f23 = __half22float2(A23);
    float a0 = f01.x, a1 = f01.y, a2 = f23.x, a3 = f23.y;
    a0 += __shfl_down(a0, 32);
    a1 += __shfl_down(a1, 32);
    a2 += __shfl_down(a2, 32);
    a3 += __shfl_down(a3, 32);
    if (lane < 32) {
      float x0 = a0, x1 = a1, x2 = a2, x3 = a3;  // w'=w/deg -> already the mean
      x0 = (x0 > 0.f) ? x0 : 0.01f * x0;    // leaky_relu(0)=0 keeps deg==0 rows 0
      x1 = (x1 > 0.f) ? x1 : 0.01f * x1;
      x2 = (x2 > 0.f) ? x2 : 0.01f * x2;
      x3 = (x3 > 0.f) ? x3 : 0.01f * x3;
      h1p8[(size_t)n * 32 + li] = enc4_e5m2(x0, x1, x2, x3);
    }
  }
}

// ---------- K4: layer-2 per-node gather fused with per-graph pooling ----------
#define NPW2 10
#define BLKS_PER_G (NODES_PER_GRAPH / (4 * NPW2))   // 50
__global__ void k_agg2(const int2* __restrict__ pay,
                       const int* __restrict__ rowD, const int* __restrict__ cntD,
                       const unsigned* __restrict__ h1p8,
                       float* __restrict__ pool) {
  int g = blockIdx.x / BLKS_PER_G;
  int chunk = blockIdx.x % BLKS_PER_G;
  int w = threadIdx.x >> 6, lane = threadIdx.x & 63;
  int li = lane & 31, half = lane >> 5;
  int nbase = g * NODES_PER_GRAPH + chunk * (4 * NPW2) + w * NPW2;
  __half2 A01 = __half2half2(__float2half(0.f));
  __half2 A23 = A01, SW = A01;
  for (int i = 0; i < NPW2; ++i) {
    int n = nbase + i;
    int beg = __builtin_amdgcn_readfirstlane(rowD[n]);
    int cnt = __builtin_amdgcn_readfirstlane(cntD[n]);
    gather_row<false>(pay, h1p8, beg, cnt, li, half, A01, A23, SW);
  }
  float2 f01 = __half22float2(A01);
  float2 f23 = __half22float2(A23);
  float s0 = f01.x, s1 = f01.y, s2 = f23.x, s3 = f23.y;
  float sc = __low2float(SW);
  s0 += __shfl_down(s0, 32);
  s1 += __shfl_down(s1, 32);
  s2 += __shfl_down(s2, 32);
  s3 += __shfl_down(s3, 32);
  sc += __shfl_down(sc, 32);
  __shared__ float sS[4 * 128];
  __shared__ float sC[4];
  if (lane < 32) {
    sS[w * 128 + 4 * li + 0] = s0;
    sS[w * 128 + 4 * li + 1] = s1;
    sS[w * 128 + 4 * li + 2] = s2;
    sS[w * 128 + 4 * li + 3] = s3;
  }
  if (lane == 0) sC[w] = sc;
  __syncthreads();
  int t = threadIdx.x;
  if (t < 128) {
    float v = sS[t] + sS[128 + t] + sS[256 + t] + sS[384 + t];
    atomicAdd(&pool[g * D + t], v);
  }
  if (t == 0) atomicAdd(&pool[B_GRAPHS * D + g], sC[0] + sC[1] + sC[2] + sC[3]);
}

// ---------- K5: head — wave-parallel, barrier-light ----------
__global__ void k_final(const float* __restrict__ poolS, const float* __restrict__ poolC,
                        const float* __restrict__ W2, const float* __restrict__ b2,
                        const float* __restrict__ W_out, const float* __restrict__ b_out,
                        const float* __restrict__ y, float* __restrict__ out) {
  __shared__ float w2o[D];
  __shared__ float s2oArr[D];
  __shared__ float s2o_sh;
  __shared__ float logits[64];
  int t = threadIdx.x;                     // 256 threads = 4 waves
  int w = t >> 6, lane = t & 63;
  if (t < D) {
    float acc = 0.f;
    for (int d = 0; d < D; ++d) acc = fmaf(W2[t * D + d], W_out[d], acc);
    w2o[t] = acc;
  } else {
    int j = t - D;
    s2oArr[j] = b2[j] * W_out[j];
  }
  __syncthreads();
  if (t < 64) {
    float v = s2oArr[lane] + s2oArr[64 + lane];
#pragma unroll
    for (int off = 32; off > 0; off >>= 1) v += __shfl_down(v, off);
    if (lane == 0) s2o_sh = v;
  }
  __syncthreads();
  float s2o = s2o_sh;
  float bout = b_out[0];
  const float invN = 1.0f / (float)NODES_PER_GRAPH;
  for (int g = w; g < B_GRAPHS; g += 4) {
    float v = poolS[g * D + lane] * w2o[lane]
            + poolS[g * D + 64 + lane] * w2o[64 + lane];
#pragma unroll
    for (int off = 32; off > 0; off >>= 1) v += __shfl_down(v, off);
    if (lane == 0) {
      float l = v * invN + poolC[g] * invN * s2o + bout;
      logits[g] = l;
      out[1 + g] = 1.0f / (1.0f + expf(-l));         // y_pred
    }
  }
  __syncthreads();
  if (t < 64) {
    float term = 0.f;
    if (lane < B_GRAPHS) {
      float l = logits[lane];
      term = fmaxf(l, 0.f) - l * y[lane] + log1pf(expf(-fabsf(l)));
    }
#pragma unroll
    for (int off = 32; off > 0; off >>= 1) term += __shfl_down(term, off);
    if (lane == 0) out[0] = term / (float)B_GRAPHS;  // loss
  }
}

extern "C" void kernel_launch(void* const* d_in, const int* in_sizes, int n_in,
                              void* d_out, int out_size, void* d_ws, size_t ws_size,
                              hipStream_t stream) {
  const int*   node_ids = (const int*)d_in[0];
  const int*   src      = (const int*)d_in[1];
  const int*   dst      = (const int*)d_in[2];
  const float* ew       = (const float*)d_in[3];
  const float* y        = (const float*)d_in[4];
  const float* embeds   = (const float*)d_in[5];
  const float* W1       = (const float*)d_in[6];
  const float* b1       = (const float*)d_in[7];
  const float* W2       = (const float*)d_in[8];
  const float* b2       = (const float*)d_in[9];
  const float* W_out    = (const float*)d_in[10];
  const float* b_out    = (const float*)d_in[11];
  float* out = (float*)d_out;
  (void)in_sizes; (void)n_in; (void)out_size; (void)ws_size;

  char* ws = (char*)d_ws;
  size_t off = 0;
  auto alloc = [&](size_t bytes) {
    size_t r = off;
    off = (off + bytes + 511) & ~(size_t)511;
    return r;
  };
  size_t o_binCur = alloc(512 * 4);
  size_t o_pool   = alloc((size_t)POOL_N * 4);
  size_t o_rowD   = alloc((size_t)(NT + 1) * 4);
  size_t o_cntD   = alloc((size_t)NT * 4);
  size_t o_P1p8   = alloc((size_t)V * 32 * 4);                    // 1.92 MB
  size_t o_h1p8   = alloc((size_t)NT * 32 * 4);                   // 12.8 MB
  size_t o_stage  = alloc((size_t)NBIN * STAGE_STRIDE * 8);       // 14.4 MB
  size_t o_pay    = alloc(((size_t)NBIN * PAY_STRIDE + PAY_TAIL) * 8);  // 16.8 MB

  int*      binCursor= (int*)(ws + o_binCur);
  float*    pool     = (float*)(ws + o_pool);
  int*      rowD     = (int*)(ws + o_rowD);
  int*      cntD     = (int*)(ws + o_cntD);
  unsigned* P1p8     = (unsigned*)(ws + o_P1p8);
  unsigned* h1p8     = (unsigned*)(ws + o_h1p8);
  int2*     stage    = (int2*)(ws + o_stage);
  int2*     pay      = (int2*)(ws + o_pay);
  int2*     payTail  = pay + (size_t)NBIN * PAY_STRIDE;

  // 5 kernels + 1 tiny memset (binCursor must be zero before k_pb's binfill blocks)
  hipMemsetAsync(binCursor, 0, 512 * 4, stream);
  k_pb<<<NFB + PROJ_BLOCKS, 512, 0, stream>>>(embeds, W1, b1, P1p8, pool, payTail,
                                              src, dst, ew, node_ids, binCursor, stage);
  k_binsort<<<NBIN, 512, 0, stream>>>(stage, binCursor, rowD, cntD, pay);
  k_agg1<<<NT / (4 * NPW1), 256, 0, stream>>>(pay, rowD, cntD, P1p8, h1p8);
  k_agg2<<<B_GRAPHS * BLKS_PER_G, 256, 0, stream>>>(pay, rowD, cntD, h1p8, pool);
  k_final<<<1, 256, 0, stream>>>(pool, pool + B_GRAPHS * D, W2, b2, W_out, b_out, y, out);
}